// Round 1
// baseline (837.229 us; speedup 1.0000x reference)
//
#include <hip/hip_runtime.h>

#define Bdim 256
#define Cdim 128
#define Hdim 1024
#define Idim 512
#define Odim 128

#define BT 64     // batch tile rows per block
#define HT 128    // hidden tile per ht step
#define HS_LD 136 // padded LDS leading dim for Hs (bf16 elems)

typedef __attribute__((ext_vector_type(8))) short short8;
typedef __attribute__((ext_vector_type(4))) float f32x4;

// fp32x8 -> bf16x8 (truncate, matches previous kernel's numerics)
__device__ __forceinline__ short8 cvt8(float4 v0, float4 v1) {
    union { unsigned int u[4]; short8 s; } r;
    r.u[0] = __builtin_amdgcn_perm(__float_as_uint(v0.y), __float_as_uint(v0.x), 0x07060302);
    r.u[1] = __builtin_amdgcn_perm(__float_as_uint(v0.w), __float_as_uint(v0.z), 0x07060302);
    r.u[2] = __builtin_amdgcn_perm(__float_as_uint(v1.y), __float_as_uint(v1.x), 0x07060302);
    r.u[3] = __builtin_amdgcn_perm(__float_as_uint(v1.w), __float_as_uint(v1.z), 0x07060302);
    return r.s;
}

__global__ __launch_bounds__(256, 2) void mlp_fused(
    const float* __restrict__ x, const float* __restrict__ w1,
    const float* __restrict__ b1, const float* __restrict__ w2,
    const float* __restrict__ b2, float* __restrict__ out)
{
    // Only the layer1->layer2 handoff lives in LDS now (17408 B).
    __shared__ unsigned short Hs[BT * HS_LD];

    const int t    = threadIdx.x;
    const int lane = t & 63;
    const int q    = lane >> 4;   // quad 0..3
    const int r16  = lane & 15;
    const int wave = t >> 6;
    const int wm   = wave >> 1;   // 0..1 -> m0 = wm*32
    const int wn   = wave & 1;    // 0..1 -> n0 = wn*64

    // XCD-aware swizzle: blocks for channels g*16..g*16+15 land on XCD g
    const int bid = blockIdx.x;
    const int g   = bid & 7;
    const int s   = bid >> 3;          // 0..63
    const int c   = g * 16 + (s & 15); // channel
    const int bt  = s >> 4;            // 0..3
    const int row0 = bt * BT;

    // Per-lane fragment base pointers (A rows for layer1; B rows for both layers).
    // Intra-block duplicate reads (2 waves share each row) hit L1/L2.
    const float* xr0 = x + ((size_t)(row0 + wm * 32 + r16) * Cdim + c) * Idim; // i=0 row
    const float* xr1 = xr0 + (size_t)16 * Cdim * Idim;                          // i=1 row
    const float* w1c = w1 + (size_t)c * Hdim * Idim;
    const float* w2r[4];
    #pragma unroll
    for (int j = 0; j < 4; ++j)
        w2r[j] = w2 + ((size_t)c * Odim + wn * 64 + j * 16 + r16) * Hdim;

    // persistent layer-2 accumulators, init with b2 broadcast
    f32x4 acc2[2][4];
    #pragma unroll
    for (int j = 0; j < 4; ++j) {
        float bv = b2[c * Odim + wn * 64 + j * 16 + r16];
        f32x4 z = {bv, bv, bv, bv};
        acc2[0][j] = z;
        acc2[1][j] = z;
    }

    for (int ht = 0; ht < Hdim / HT; ++ht) {
        f32x4 acc1[2][4];
        #pragma unroll
        for (int i = 0; i < 2; ++i)
            #pragma unroll
            for (int j = 0; j < 4; ++j) acc1[i][j] = (f32x4){0.f, 0.f, 0.f, 0.f};

        const float* w1r0 = w1c + (size_t)(ht * HT + wn * 64 + r16) * Idim;

        // Layer 1: barrier-free streaming K-loop, fragments straight from global.
        // unroll 2 keeps ~2 iterations of loads in flight without register blowup.
        #pragma unroll 2
        for (int ks = 0; ks < Idim / 32; ++ks) {
            const int k0 = ks * 32 + q * 8;
            short8 a[2], b[4];
            a[0] = cvt8(*(const float4*)(xr0 + k0), *(const float4*)(xr0 + k0 + 4));
            a[1] = cvt8(*(const float4*)(xr1 + k0), *(const float4*)(xr1 + k0 + 4));
            #pragma unroll
            for (int j = 0; j < 4; ++j) {
                const float* p = w1r0 + (size_t)(j * 16) * Idim + k0;
                b[j] = cvt8(*(const float4*)p, *(const float4*)(p + 4));
            }
            #pragma unroll
            for (int i = 0; i < 2; ++i)
                #pragma unroll
                for (int j = 0; j < 4; ++j)
                    acc1[i][j] = __builtin_amdgcn_mfma_f32_16x16x32_bf16(a[i], b[j], acc1[i][j], 0, 0, 0);
        }

        __syncthreads();   // previous ht's layer-2 reads of Hs are done
        // epilogue layer 1: Hs = bf16(relu(acc1 + b1))
        #pragma unroll
        for (int j = 0; j < 4; ++j) {
            const int n = wn * 64 + j * 16 + r16;
            const float b1v = b1[c * Hdim + ht * HT + n];
            #pragma unroll
            for (int i = 0; i < 2; ++i) {
                #pragma unroll
                for (int r = 0; r < 4; ++r) {
                    const int m = wm * 32 + i * 16 + q * 4 + r;
                    const float hv = fmaxf(acc1[i][j][r] + b1v, 0.f);
                    Hs[m * HS_LD + n] = (unsigned short)(__float_as_uint(hv) >> 16);
                }
            }
        }
        __syncthreads();

        // Layer 2 partial: acc2 += Hs (64x128) * w2^T, B-frags straight from global.
        #pragma unroll
        for (int ks = 0; ks < HT / 32; ++ks) {
            const int k0 = ks * 32 + q * 8;
            short8 a[2], b[4];
            #pragma unroll
            for (int i = 0; i < 2; ++i)
                a[i] = *(const short8*)&Hs[(wm * 32 + i * 16 + r16) * HS_LD + k0];
            #pragma unroll
            for (int j = 0; j < 4; ++j) {
                const float* p = w2r[j] + ht * HT + k0;
                b[j] = cvt8(*(const float4*)p, *(const float4*)(p + 4));
            }
            #pragma unroll
            for (int i = 0; i < 2; ++i)
                #pragma unroll
                for (int j = 0; j < 4; ++j)
                    acc2[i][j] = __builtin_amdgcn_mfma_f32_16x16x32_bf16(a[i], b[j], acc2[i][j], 0, 0, 0);
        }
    }

    // store: out[b, o, c] — XCD swizzle groups the 16 c-writers of each 64B line
    #pragma unroll
    for (int i = 0; i < 2; ++i)
        #pragma unroll
        for (int j = 0; j < 4; ++j)
            #pragma unroll
            for (int r = 0; r < 4; ++r) {
                const int bb = row0 + wm * 32 + i * 16 + q * 4 + r;
                const int o  = wn * 64 + j * 16 + r16;
                out[(size_t)bb * (Odim * Cdim) + o * Cdim + c] = acc2[i][j][r];
            }
}

extern "C" void kernel_launch(void* const* d_in, const int* in_sizes, int n_in,
                              void* d_out, int out_size, void* d_ws, size_t ws_size,
                              hipStream_t stream) {
    const float* x  = (const float*)d_in[0];
    const float* w1 = (const float*)d_in[1];
    const float* b1 = (const float*)d_in[2];
    const float* w2 = (const float*)d_in[3];
    const float* b2 = (const float*)d_in[4];
    float* out = (float*)d_out;
    mlp_fused<<<dim3(512), dim3(256), 0, stream>>>(x, w1, b1, w2, b2, out);
}

// Round 2
// 518.989 us; speedup vs baseline: 1.6132x; 1.6132x over previous
//
#include <hip/hip_runtime.h>

#define Bdim 256
#define Cdim 128
#define Hdim 1024
#define Idim 512
#define Odim 128

#define BT 64     // batch tile rows per block
#define HT 128    // hidden tile
#define BK 64     // K tile for layer 1

// padded LDS leading dims (keep 16B alignment: LD*2 % 16 == 0, LD%32 != 0 banks)
#define XS_LD  72
#define W1S_LD 72
#define W2S_LD 136
#define HS_LD  136

typedef __attribute__((ext_vector_type(8))) short short8;
typedef __attribute__((ext_vector_type(4))) float f32x4;

#define FENCE()  asm volatile("" ::: "memory")
#define BAR()    __builtin_amdgcn_s_barrier()
#define LGKM0()  asm volatile("s_waitcnt lgkmcnt(0)" ::: "memory")

__device__ __forceinline__ uint2 cvt4(float4 v) {
    unsigned int lo = __builtin_amdgcn_perm(__float_as_uint(v.y), __float_as_uint(v.x), 0x07060302);
    unsigned int hi = __builtin_amdgcn_perm(__float_as_uint(v.w), __float_as_uint(v.z), 0x07060302);
    return make_uint2(lo, hi);
}

__global__ __launch_bounds__(256, 2) void mlp_fused(
    const float* __restrict__ x, const float* __restrict__ w1,
    const float* __restrict__ b1, const float* __restrict__ w2,
    const float* __restrict__ b2, float* __restrict__ out)
{
    __shared__ unsigned char smem[52224];
    unsigned short* Xs  = (unsigned short*)smem;            // [64][72]   9216 B
    unsigned short* W1s = (unsigned short*)(smem + 9216);   // [128][72]  18432 B
    unsigned short* W2s = (unsigned short*)smem;            // [128][136] 34816 B (aliases Xs+W1s)
    unsigned short* Hs  = (unsigned short*)(smem + 34816);  // [64][136]  17408 B

    const int t    = threadIdx.x;
    const int lane = t & 63;
    const int q    = lane >> 4;   // quad 0..3
    const int r16  = lane & 15;
    const int wave = t >> 6;
    const int wm   = wave >> 1;   // 0..1 -> m0 = wm*32
    const int wn   = wave & 1;    // 0..1 -> n0 = wn*64

    // XCD-aware swizzle: blocks for channels g*16..g*16+15 land on XCD g
    const int bid = blockIdx.x;
    const int g   = bid & 7;
    const int s   = bid >> 3;          // 0..63
    const int c   = g * 16 + (s & 15); // channel
    const int bt  = s >> 4;            // 0..3
    const int row0 = bt * BT;

    // staging thread decomposition
    const int tx    = t & 15;   // 16 thr * float4 = 64 cols (Xs/W1s)
    const int trow  = t >> 4;   // 16 rows per pass
    const int tx32  = t & 31;   // 32 thr * float4 = 128 cols (W2s)
    const int trow8 = t >> 5;   // 8 rows per pass

    const float* xbase  = x  + ((size_t)row0 * Cdim + c) * Idim;
    const float* w1base = w1 + (size_t)c * Hdim * Idim;
    const float* w2base = w2 + (size_t)c * Odim * Hdim;

    // persistent layer-2 accumulators, init with b2 broadcast (n depends on j only)
    f32x4 acc2[2][4];
    #pragma unroll
    for (int j = 0; j < 4; ++j) {
        float bv = b2[c * Odim + wn * 64 + j * 16 + r16];
        f32x4 z = {bv, bv, bv, bv};
        acc2[0][j] = z;
        acc2[1][j] = z;
    }

    // prefetch registers: next W1/X k-tile, and the W2 tile at ht boundaries
    float4 pw[8], px[4], qw[16];

    // prologue: issue loads for (ht=0, kt=0); they land under acc2 init & first barrier
    #pragma unroll
    for (int p = 0; p < 8; ++p)
        pw[p] = *(const float4*)(w1base + (size_t)(trow + p * 16) * Idim + tx * 4);
    #pragma unroll
    for (int p = 0; p < 4; ++p)
        px[p] = *(const float4*)(xbase + (size_t)(trow + p * 16) * (Cdim * Idim) + tx * 4);

    for (int ht = 0; ht < Hdim / HT; ++ht) {
        f32x4 acc1[2][4];
        #pragma unroll
        for (int i = 0; i < 2; ++i)
            #pragma unroll
            for (int j = 0; j < 4; ++j) acc1[i][j] = (f32x4){0.f, 0.f, 0.f, 0.f};

        for (int kt = 0; kt < Idim / BK; ++kt) {
            // WAR barrier: all waves finished reading region A (prev kt's Xs/W1s,
            // or prev ht's W2s which aliases it). No vmcnt drain — prefetch stays in flight.
            FENCE();
            BAR();
            // write current tile (compiler emits counted vmcnt for pw/px arrivals)
            #pragma unroll
            for (int p = 0; p < 8; ++p)
                *(uint2*)&W1s[(trow + p * 16) * W1S_LD + tx * 4] = cvt4(pw[p]);
            #pragma unroll
            for (int p = 0; p < 4; ++p)
                *(uint2*)&Xs[(trow + p * 16) * XS_LD + tx * 4] = cvt4(px[p]);
            // issue next phase's loads — they fly under the MFMA compute below
            if (kt < Idim / BK - 1) {
                #pragma unroll
                for (int p = 0; p < 8; ++p)
                    pw[p] = *(const float4*)(w1base + (size_t)(ht * HT + trow + p * 16) * Idim + (kt + 1) * BK + tx * 4);
                #pragma unroll
                for (int p = 0; p < 4; ++p)
                    px[p] = *(const float4*)(xbase + (size_t)(trow + p * 16) * (Cdim * Idim) + (kt + 1) * BK + tx * 4);
            } else {
                // last k-tile of this ht: prefetch the W2 tile instead
                #pragma unroll
                for (int p = 0; p < 16; ++p)
                    qw[p] = *(const float4*)(w2base + (size_t)(trow8 + p * 8) * Hdim + ht * HT + tx32 * 4);
            }
            LGKM0();   // ds_writes visible
            BAR();
            // compute kt
            #pragma unroll
            for (int ks = 0; ks < 2; ++ks) {
                int k0 = ks * 32 + q * 8;
                short8 a[2], b[4];
                #pragma unroll
                for (int i = 0; i < 2; ++i)
                    a[i] = *(const short8*)&Xs[(wm * 32 + i * 16 + r16) * XS_LD + k0];
                #pragma unroll
                for (int j = 0; j < 4; ++j)
                    b[j] = *(const short8*)&W1s[(wn * 64 + j * 16 + r16) * W1S_LD + k0];
                #pragma unroll
                for (int i = 0; i < 2; ++i)
                    #pragma unroll
                    for (int j = 0; j < 4; ++j)
                        acc1[i][j] = __builtin_amdgcn_mfma_f32_16x16x32_bf16(a[i], b[j], acc1[i][j], 0, 0, 0);
            }
        }

        // all waves done reading Xs/W1s; prev-ht Hs fully consumed
        FENCE();
        BAR();

        // stage W2s (128 o x 128 h) into region A from prefetch regs
        #pragma unroll
        for (int p = 0; p < 16; ++p)
            *(uint2*)&W2s[(trow8 + p * 8) * W2S_LD + tx32 * 4] = cvt4(qw[p]);

        // epilogue layer 1: Hs = bf16(relu(acc1 + b1))
        #pragma unroll
        for (int j = 0; j < 4; ++j) {
            int n = wn * 64 + j * 16 + r16;
            float b1v = b1[c * Hdim + ht * HT + n];
            #pragma unroll
            for (int i = 0; i < 2; ++i) {
                #pragma unroll
                for (int r = 0; r < 4; ++r) {
                    int m = wm * 32 + i * 16 + q * 4 + r;
                    float hv = fmaxf(acc1[i][j][r] + b1v, 0.f);
                    Hs[m * HS_LD + n] = (unsigned short)(__float_as_uint(hv) >> 16);
                }
            }
        }

        // issue next ht's first W1/X tile — flies under the layer-2 MFMA below
        if (ht < Hdim / HT - 1) {
            #pragma unroll
            for (int p = 0; p < 8; ++p)
                pw[p] = *(const float4*)(w1base + (size_t)((ht + 1) * HT + trow + p * 16) * Idim + tx * 4);
            #pragma unroll
            for (int p = 0; p < 4; ++p)
                px[p] = *(const float4*)(xbase + (size_t)(trow + p * 16) * (Cdim * Idim) + tx * 4);
        }

        LGKM0();   // W2s + Hs writes visible
        BAR();

        // layer 2 partial: acc2 += Hs (64x128) * W2s^T (128h x 128o)
        #pragma unroll
        for (int ks = 0; ks < 4; ++ks) {
            int k0 = ks * 32 + q * 8;
            short8 a[2], b[4];
            #pragma unroll
            for (int i = 0; i < 2; ++i)
                a[i] = *(const short8*)&Hs[(wm * 32 + i * 16 + r16) * HS_LD + k0];
            #pragma unroll
            for (int j = 0; j < 4; ++j)
                b[j] = *(const short8*)&W2s[(wn * 64 + j * 16 + r16) * W2S_LD + k0];
            #pragma unroll
            for (int i = 0; i < 2; ++i)
                #pragma unroll
                for (int j = 0; j < 4; ++j)
                    acc2[i][j] = __builtin_amdgcn_mfma_f32_16x16x32_bf16(a[i], b[j], acc2[i][j], 0, 0, 0);
        }
    }

    // store: out[b, o, c] = b*O*C + o*C + c   (scattered dwords; XCD swizzle
    // groups the 16 c-writers of each 64B line onto one XCD for L2 merging)
    #pragma unroll
    for (int i = 0; i < 2; ++i)
        #pragma unroll
        for (int j = 0; j < 4; ++j)
            #pragma unroll
            for (int r = 0; r < 4; ++r) {
                int bb = row0 + wm * 32 + i * 16 + q * 4 + r;
                int o  = wn * 64 + j * 16 + r16;
                out[(size_t)bb * (Odim * Cdim) + o * Cdim + c] = acc2[i][j][r];
            }
}

extern "C" void kernel_launch(void* const* d_in, const int* in_sizes, int n_in,
                              void* d_out, int out_size, void* d_ws, size_t ws_size,
                              hipStream_t stream) {
    const float* x  = (const float*)d_in[0];
    const float* w1 = (const float*)d_in[1];
    const float* b1 = (const float*)d_in[2];
    const float* w2 = (const float*)d_in[3];
    const float* b2 = (const float*)d_in[4];
    float* out = (float*)d_out;
    mlp_fused<<<dim3(512), dim3(256), 0, stream>>>(x, w1, b1, w2, b2, out);
}